// Round 9
// baseline (239.036 us; speedup 1.0000x reference)
//
#include <hip/hip_runtime.h>

// Dims: B=2, L=32, C=32, S=64, W=64, R=32, MH=32. BL=64, SW=4096.
//
// 6-dispatch pipeline, all bodies software-pipelined (prefetch-under-compute,
// NO cross-block sync):
//  k_mixprep: mix 2 segs/block + DFT coeff mats + weff
//  k_zq:      4 (bl,c) units/block (same c -> coeffs loaded once) + MLP tail
//  k_scan:    4-way split-chain scan, bf16-packed output
//  k_rec:     4 units/block (same c), rec GEMMs -> hsp
//  k_conv:    2 slabs/block, slab-1 register-prefetched under slab-0 MFMA
//  k_ln:      2 planes/block, parallel stats reduce in waves 0/1

typedef __attribute__((ext_vector_type(8))) short short8;
typedef __attribute__((ext_vector_type(4))) float floatx4;

__device__ __forceinline__ unsigned pack_bf16(float re, float im) {
  unsigned a = __float_as_uint(re), b = __float_as_uint(im);
  a = (a + 0x7FFFu + ((a >> 16) & 1u)) >> 16;
  b = (b + 0x7FFFu + ((b >> 16) & 1u)) >> 16;
  return a | (b << 16);
}
__device__ __forceinline__ unsigned short bf16r(float v) {
  unsigned a = __float_as_uint(v);
  return (unsigned short)((a + 0x7FFFu + ((a >> 16) & 1u)) >> 16);
}

// ------------------------------------------------------------- k_mixprep
// mix: blocks 0..511 (2 segments each, seg-1 x prefetched under seg-0);
// DFT: 512..575; weff: 576..611.
__global__ __launch_bounds__(256) void k_mixprep(
    const float* __restrict__ x, const float* __restrict__ pWr,
    const float* __restrict__ pWi,
    const float* __restrict__ U_re, const float* __restrict__ U_im,
    const float* __restrict__ V_re, const float* __restrict__ V_im,
    const float* __restrict__ projc_w, const float* __restrict__ convr_w,
    const float* __restrict__ convi_w,
    unsigned* __restrict__ hs, float* __restrict__ ctxp,
    unsigned* __restrict__ zqA, unsigned* __restrict__ recA,
    unsigned* __restrict__ recB, unsigned* __restrict__ Wtb) {
  __shared__ __align__(16) char smem[33280];
  const int tid = threadIdx.x;
  if (blockIdx.x < 512) {                     // ---------------- mix body
    unsigned* xb_s = (unsigned*)smem;                       // [256*20] 20 KB
    float(*red)[16][2] = (float(*)[16][2])(smem + 20480);   // [16][16][2] 2 KB
    unsigned* outb = (unsigned*)smem;                       // [32][260] 33 KB
    const int bl = blockIdx.x >> 3;
    const int seg0 = blockIdx.x & 7;
    const int lane = tid & 63, wv = tid >> 6;
    const int qd = lane >> 4, ln = lane & 15;
    short8 arL, aiL, arH, aiH;
#pragma unroll
    for (int j = 0; j < 8; ++j) {
      int ci = qd * 8 + j;
      ((short*)&arL)[j] = (short)bf16r(pWr[ci * 32 + ln]);
      ((short*)&aiL)[j] = (short)bf16r(pWi[ci * 32 + ln]);
      ((short*)&arH)[j] = (short)bf16r(pWr[ci * 32 + 16 + ln]);
      ((short*)&aiH)[j] = (short)bf16r(pWi[ci * 32 + 16 + ln]);
    }
    float4 pa[4], pb[4];
    {
      const float* xb = x + (size_t)bl * 131072 + seg0 * 256;
#pragma unroll
      for (int t = 0; t < 4; ++t) {
        int i = t * 256 + tid;
        int c2 = i & 15, g4 = i >> 4;
        pa[t] = *(const float4*)(xb + (2 * c2) * 4096 + g4 * 4);
        pb[t] = *(const float4*)(xb + (2 * c2 + 1) * 4096 + g4 * 4);
      }
    }
#pragma unroll
    for (int u = 0; u < 2; ++u) {
      const int seg = seg0 + u * 8;
      const int pxbase = seg * 256;
      if (u) __syncthreads();       // prior hs-store outb reads complete
      float csa = 0.f, csb = 0.f;
#pragma unroll
      for (int t = 0; t < 4; ++t) {
        int i = t * 256 + tid;
        int c2 = i & 15, g4 = i >> 4;
        float4 a = pa[t], b = pb[t];
        csa += a.x + a.y + a.z + a.w;
        csb += b.x + b.y + b.z + b.w;
#pragma unroll
        for (int j = 0; j < 4; ++j) {
          int px = g4 * 4 + j;
          xb_s[px * 20 + (((c2 >> 2) ^ (px & 3)) << 2) + (c2 & 3)] =
              pack_bf16(((const float*)&a)[j], ((const float*)&b)[j]);
        }
      }
      red[tid & 15][tid >> 4][0] = csa;
      red[tid & 15][tid >> 4][1] = csb;
      if (u == 0) {                 // prefetch seg1 x under this seg's work
        const float* xb1 = x + (size_t)bl * 131072 + (seg0 + 8) * 256;
#pragma unroll
        for (int t = 0; t < 4; ++t) {
          int i = t * 256 + tid;
          int c2 = i & 15, g4 = i >> 4;
          pa[t] = *(const float4*)(xb1 + (2 * c2) * 4096 + g4 * 4);
          pb[t] = *(const float4*)(xb1 + (2 * c2 + 1) * 4096 + g4 * 4);
        }
      }
      __syncthreads();
      if (tid < 32) {               // ctx partial for this (bl, seg)
        int c2 = tid >> 1, part = tid & 1;
        float s = 0.f;
#pragma unroll
        for (int w = 0; w < 16; ++w) s += red[c2][w][part];
        ctxp[(bl * 16 + seg) * 32 + 2 * c2 + part] = s;
      }
      floatx4 RL[4], IL[4], RH[4], IH[4];
#pragma unroll
      for (int pt = 0; pt < 4; ++pt) {
        int pxt = wv * 4 + pt;
        int pxl = pxt * 16 + ln;
        short8 bfr = *(const short8*)&xb_s[pxl * 20 + ((qd ^ (pxl & 3)) << 2)];
        floatx4 z4 = {0.f, 0.f, 0.f, 0.f};
        RL[pt] = __builtin_amdgcn_mfma_f32_16x16x32_bf16(arL, bfr, z4, 0, 0, 0);
        IL[pt] = __builtin_amdgcn_mfma_f32_16x16x32_bf16(aiL, bfr, z4, 0, 0, 0);
        RH[pt] = __builtin_amdgcn_mfma_f32_16x16x32_bf16(arH, bfr, z4, 0, 0, 0);
        IH[pt] = __builtin_amdgcn_mfma_f32_16x16x32_bf16(aiH, bfr, z4, 0, 0, 0);
      }
      __syncthreads();              // xb_s dead; reuse as outb
#pragma unroll
      for (int pt = 0; pt < 4; ++pt) {
        int px = (wv * 4 + pt) * 16 + ln;
#pragma unroll
        for (int j = 0; j < 4; ++j) {
          outb[(qd * 4 + j) * 260 + px] = pack_bf16(RL[pt][j], IL[pt][j]);
          outb[(16 + qd * 4 + j) * 260 + px] = pack_bf16(RH[pt][j], IH[pt][j]);
        }
      }
      __syncthreads();
      unsigned* ho = hs + (size_t)bl * 131072 + pxbase;
      const int px4 = tid & 63, dg = tid >> 6;
#pragma unroll
      for (int dd = 0; dd < 8; ++dd) {
        int d = dg * 8 + dd;
        uint4 v = *(const uint4*)&outb[d * 260 + px4 * 4];
        *(uint4*)(ho + d * 4096 + px4 * 4) = v;
      }
    }
  } else if (blockIdx.x < 576) {              // ---------------- DFT body
    float2* A2 = (float2*)smem;               // [2048] 16 KB
    float2* tw = (float2*)(smem + 16384);     // [64]
    const int id = blockIdx.x - 512;
    const int c = id >> 1, src = id & 1;      // 0=U(plus), 1=V(minus)
    const float* Ar = (src ? V_re : U_re) + c * 2048;
    const float* Ai = (src ? V_im : U_im) + c * 2048;
    if (tid < 64) {
      float sa, ca;
      sincosf((float)tid * 0.09817477042468103f, &sa, &ca);
      tw[tid] = make_float2(ca, sa);
    }
#pragma unroll
    for (int t = 0; t < 8; ++t) {
      int idx = t * 256 + tid;
      A2[idx] = make_float2(Ar[idx], Ai[idx]);
    }
    __syncthreads();
    const int kw = tid >> 2, mg = tid & 3;
    float sr[8] = {0.f, 0.f, 0.f, 0.f, 0.f, 0.f, 0.f, 0.f};
    float si[8] = {0.f, 0.f, 0.f, 0.f, 0.f, 0.f, 0.f, 0.f};
#pragma unroll 4
    for (int n = 0; n < 64; ++n) {
      float2 w = tw[(kw * n) & 63];
      float ws = src ? -w.y : w.y;
#pragma unroll
      for (int t4 = 0; t4 < 4; ++t4) {
        float4 q = *(const float4*)&A2[n * 32 + mg * 8 + t4 * 2];
        sr[2 * t4]     += q.x * w.x - q.y * ws;
        si[2 * t4]     += q.x * ws + q.y * w.x;
        sr[2 * t4 + 1] += q.z * w.x - q.w * ws;
        si[2 * t4 + 1] += q.z * ws + q.w * w.x;
      }
    }
#pragma unroll
    for (int j = 0; j < 8; ++j) {
      float r = sr[j] * 0.125f, i2 = si[j] * 0.125f;
      int m = mg * 8 + j;
      unsigned p_ri  = pack_bf16(r, i2);
      unsigned p_rmi = pack_bf16(r, -i2);
      unsigned p_ir  = pack_bf16(i2, r);
      unsigned p_mir = pack_bf16(-i2, r);
      if (src == 0) {                         // F+ . U
        zqA[((c * 4 + 2) * 32 + m) * 64 + kw] = p_ri;   // A3
        zqA[((c * 4 + 3) * 32 + m) * 64 + kw] = p_mir;  // A4
        recA[((c * 2 + 0) * 64 + kw) * 32 + m] = p_rmi; // A5
        recA[((c * 2 + 1) * 64 + kw) * 32 + m] = p_ir;  // A6
      } else {                                // F- . V
        zqA[((c * 4 + 0) * 32 + m) * 64 + kw] = p_rmi;  // A1
        zqA[((c * 4 + 1) * 32 + m) * 64 + kw] = p_ir;   // A2
        recB[((c * 2 + 0) * 64 + kw) * 32 + m] = p_ri;  // B5
        recB[((c * 2 + 1) * 64 + kw) * 32 + m] = p_mir; // B6
      }
    }
  } else {                                    // ---------------- weff body
    int gid = (blockIdx.x - 576) * 256 + tid;   // (co*9+tap)*32 + ci
    if (gid < 9216) {
      int co = gid / 288;
      int r2 = gid - co * 288;
      int tap = r2 >> 5, ci = r2 & 31;
      float sr = 0.f, si = 0.f;
      for (int m = 0; m < 32; ++m) {
        sr += projc_w[co * 64 + m]      * convr_w[(m * 32 + ci) * 9 + tap];
        si += projc_w[co * 64 + 32 + m] * convi_w[(m * 32 + ci) * 9 + tap];
      }
      Wtb[gid] = pack_bf16(sr, si);
    }
  }
}

// --------------- MFMA zq: 512 blocks x 4 units (i0+512u; same c so coeff
// fragments load once; unit u+1 hs loads issued before unit-u GEMMs) +
// 64 MLP tail blocks (512..575).
__global__ __launch_bounds__(256) void k_zq(
    const unsigned* __restrict__ hs, const short* __restrict__ zqA,
    float2* __restrict__ zq,
    const float* __restrict__ ctxp, const float* __restrict__ listT,
    const float* __restrict__ plb, const float* __restrict__ dmod,
    const float* __restrict__ W1, const float* __restrict__ b1,
    const float* __restrict__ W2, const float* __restrict__ b2,
    const float* __restrict__ fscale,
    float2* __restrict__ lam, float* __restrict__ gam) {
  __shared__ unsigned HsB[4096];   // [s][w-chunks xor-swizzled], 16 KB
  __shared__ unsigned T2[2048];    // [q][s-chunks xor-swizzled], 8 KB
  __shared__ float mid_s[32];
  __shared__ float ctxs[32];
  const int tid = threadIdx.x;
  if (blockIdx.x >= 512) {         // ---- MLP -> lam/gam (ctx ready: mix done)
    int bl = blockIdx.x - 512;
    float dt = listT[bl];
    if (tid < 32) {                // sum the 16 per-segment ctx partials
      float s = 0.f;
#pragma unroll
      for (int sg = 0; sg < 16; ++sg) s += ctxp[(bl * 16 + sg) * 32 + tid];
      ctxs[tid] = s * (1.f / 4096.f);
    }
    __syncthreads();
    if (tid < 32) {
      float a = b1[tid];
      for (int j = 0; j < 32; ++j) a += ctxs[j] * W1[j * 32 + tid];
      a += dt * W1[1024 + tid];
      mid_s[tid] = tanhf(a);
    }
    __syncthreads();
    float fs = fscale[0];
#pragma unroll
    for (int u = 0; u < 4; ++u) {
      int cr = u * 256 + tid;
      int col = cr * 2;
      float m0 = b2[col], m1 = b2[col + 1];
      for (int h = 0; h < 32; ++h) {
        float mh = mid_s[h];
        float2 w2 = *(const float2*)&W2[h * 2048 + col];
        m0 += mh * w2.x;
        m1 += mh * w2.y;
      }
      float dnu = fs * tanhf(m0);
      float dth = fs * tanhf(m1);
      float nub = expf(plb[cr] + dmod[cr]);
      float thb = expf(plb[1024 + cr] + dmod[1024 + cr]);
      float nut = fmaxf(nub * dt + dnu, 1e-6f);
      float tht = thb * dt + dth;
      float e = expf(-nut);
      float sa, ca;
      sincosf(tht, &sa, &ca);
      float g = sqrtf(fmaxf(1.f - expf(-2.f * nut), 1e-12f));
      int o = bl * 1024 + cr;
      lam[o] = make_float2(e * ca, e * sa);
      gam[o] = g;
    }
    return;
  }
  const int i0 = blockIdx.x;
  const int c = i0 & 31;
  const int lane = tid & 63, wv = tid >> 6;
  const int qd = lane >> 4, ln = lane & 15;
  const int mt = wv >> 1, nth = wv & 1;
  const short* zA = zqA + (size_t)c * 4 * 32 * 128;
  short8 a1[4], a2[4], a3[4], a4[4];
#pragma unroll
  for (int t = 0; t < 4; ++t) {
    int row = mt * 16 + ln;
    a1[t] = *(const short8*)(zA + (0 * 32 + row) * 128 + t * 32 + qd * 8);
    a2[t] = *(const short8*)(zA + (1 * 32 + row) * 128 + t * 32 + qd * 8);
    a3[t] = *(const short8*)(zA + (2 * 32 + row) * 128 + t * 32 + qd * 8);
    a4[t] = *(const short8*)(zA + (3 * 32 + row) * 128 + t * 32 + qd * 8);
  }
  uint4 pre[4];
  {
    const uint4* hp = (const uint4*)(hs + (size_t)i0 * 4096);
#pragma unroll
    for (int it = 0; it < 4; ++it) pre[it] = hp[tid + it * 256];
  }
#pragma unroll
  for (int u = 0; u < 4; ++u) {
    const int blc = i0 + u * 512;
#pragma unroll
    for (int it = 0; it < 4; ++it) {
      int i4 = tid + it * 256;
      int s = i4 >> 4, w4 = i4 & 15;
      *(uint4*)&HsB[s * 64 + ((w4 ^ (s & 15)) << 2)] = pre[it];
    }
    if (u < 3) {                   // issue next-unit loads; fly under GEMMs
      const uint4* hp = (const uint4*)(hs + (size_t)(i0 + (u + 1) * 512) * 4096);
#pragma unroll
      for (int it = 0; it < 4; ++it) pre[it] = hp[tid + it * 256];
    }
    __syncthreads();
#pragma unroll
    for (int nti = 0; nti < 2; ++nti) {
      int nt = nth * 2 + nti;
      int n = nt * 16 + ln;
      floatx4 accr = {0.f, 0.f, 0.f, 0.f}, acci = {0.f, 0.f, 0.f, 0.f};
#pragma unroll
      for (int t = 0; t < 4; ++t) {
        short8 b = *(const short8*)&HsB[n * 64 + (((4 * t + qd) ^ (n & 15)) << 2)];
        accr = __builtin_amdgcn_mfma_f32_16x16x32_bf16(a1[t], b, accr, 0, 0, 0);
        acci = __builtin_amdgcn_mfma_f32_16x16x32_bf16(a2[t], b, acci, 0, 0, 0);
      }
#pragma unroll
      for (int j = 0; j < 4; ++j) {
        int q = mt * 16 + qd * 4 + j;
        int s = n;
        T2[q * 64 + (((s >> 2) ^ (q & 15)) << 2) + (s & 3)] =
            pack_bf16(accr[j], acci[j]);
      }
    }
    __syncthreads();
    {
      const int mt2 = wv >> 1, nt2 = wv & 1;
      int n = nt2 * 16 + ln;
      floatx4 zr = {0.f, 0.f, 0.f, 0.f}, zi = {0.f, 0.f, 0.f, 0.f};
#pragma unroll
      for (int t = 0; t < 4; ++t) {
        short8 b = *(const short8*)&T2[n * 64 + (((4 * t + qd) ^ (n & 15)) << 2)];
        zr = __builtin_amdgcn_mfma_f32_16x16x32_bf16(a3[t], b, zr, 0, 0, 0);
        zi = __builtin_amdgcn_mfma_f32_16x16x32_bf16(a4[t], b, zi, 0, 0, 0);
      }
      float2* zo = zq + (size_t)blc * 1024;
#pragma unroll
      for (int j = 0; j < 4; ++j) {
        int r = mt2 * 16 + qd * 4 + j;
        zo[r * 32 + n] = make_float2(zr[j], zi[j]);
      }
    }
    if (u < 3) __syncthreads();    // T2/HsB reads done before next writes
  }
}

// --------------------- linear scan: 4-way split chains + LDS carry fixup.
__global__ __launch_bounds__(256) void k_scan(const float2* __restrict__ lam,
                                              const float* __restrict__ gam,
                                              const float2* __restrict__ zin,
                                              unsigned* __restrict__ zsp,
                                              int zst) {
  __shared__ float2 se[4][64];
  __shared__ float2 pe[4][64];
  __shared__ float2 cr_s[4][64];
  const int bc = blockIdx.x >> 4;            // b*32 + c
  const int b = bc >> 5, c = bc & 31;
  const int rq0 = (blockIdx.x & 15) * 64;
  const int seg = threadIdx.x >> 6, u = threadIdx.x & 63;
  const int rq = rq0 + u, r = rq >> 5;
  const int t0 = seg * 8;
  float2 vv[8], ll[8];
  float gg[8];
#pragma unroll
  for (int i = 0; i < 8; ++i) {              // independent loads, all in flight
    int t = b * 32 + t0 + i;
    vv[i] = zin[((size_t)t * 32 + c) * 1024 + rq];
    ll[i] = lam[t * 1024 + c * 32 + r];
    gg[i] = gam[t * 1024 + c * 32 + r];
  }
  float2 s = make_float2(0.f, 0.f), P = make_float2(1.f, 0.f);
  float2 zloc[8], Ps[8];
#pragma unroll
  for (int i = 0; i < 8; ++i) {
    float2 lm = ll[i];
    float nr = lm.x * s.x - lm.y * s.y + gg[i] * vv[i].x;
    float ni = lm.x * s.y + lm.y * s.x + gg[i] * vv[i].y;
    s = make_float2(nr, ni);
    float pr = P.x * lm.x - P.y * lm.y;
    float pi = P.x * lm.y + P.y * lm.x;
    P = make_float2(pr, pi);
    zloc[i] = s;
    Ps[i] = P;
  }
  se[seg][u] = s;
  pe[seg][u] = P;
  __syncthreads();
  if (threadIdx.x < 64) {                    // per-chain carry combine
    float2 c1 = se[0][u];
    float2 p1 = pe[1][u], s1 = se[1][u];
    float2 c2 = make_float2(s1.x + p1.x * c1.x - p1.y * c1.y,
                            s1.y + p1.x * c1.y + p1.y * c1.x);
    float2 p2 = pe[2][u], s2 = se[2][u];
    float2 c3 = make_float2(s2.x + p2.x * c2.x - p2.y * c2.y,
                            s2.y + p2.x * c2.y + p2.y * c2.x);
    cr_s[0][u] = make_float2(0.f, 0.f);
    cr_s[1][u] = c1;
    cr_s[2][u] = c2;
    cr_s[3][u] = c3;
  }
  __syncthreads();
  float2 cr = cr_s[seg][u];
#pragma unroll
  for (int i = 0; i < 8; ++i) {
    float zr = zloc[i].x + Ps[i].x * cr.x - Ps[i].y * cr.y;
    float zi = zloc[i].y + Ps[i].x * cr.y + Ps[i].y * cr.x;
    size_t idx = ((size_t)(b * 32 + t0 + i) * 32 + c) * 1024 + rq;
    zsp[idx * zst] = pack_bf16(zr, zi);
  }
}

// --------------- MFMA rec: 512 blocks x 4 units (i0+512u; same c so recA
// fragments load once; next-unit zs loads fly under current GEMMs).
__global__ __launch_bounds__(256) void k_rec(const unsigned* __restrict__ zs,
                                             int zst,
                                             const short* __restrict__ recA,
                                             const short* __restrict__ recB,
                                             unsigned* __restrict__ hsp) {
  __shared__ unsigned zB[1024];
  __shared__ unsigned P[2048];
  const int i0 = blockIdx.x;
  const int c = i0 & 31;
  const int tid = threadIdx.x;
  const int lane = tid & 63, wv = tid >> 6;
  const int qd = lane >> 4, ln = lane & 15;
  const short* rA = recA + (size_t)c * 2 * 64 * 64;
  short8 a5[2], a6[2];
#pragma unroll
  for (int t = 0; t < 2; ++t) {
    int row = wv * 16 + ln;
    a5[t] = *(const short8*)(rA + (0 * 64 + row) * 64 + t * 32 + qd * 8);
    a6[t] = *(const short8*)(rA + (1 * 64 + row) * 64 + t * 32 + qd * 8);
  }
  const short* rB = recB + (size_t)c * 2 * 64 * 64;
  unsigned pre[4];
  {
    const unsigned* zp = zs + (size_t)i0 * 1024 * zst;
#pragma unroll
    for (int it = 0; it < 4; ++it)
      pre[it] = zp[(size_t)(tid + it * 256) * zst];
  }
#pragma unroll
  for (int u = 0; u < 4; ++u) {
    const int blc = i0 + u * 512;
#pragma unroll
    for (int it = 0; it < 4; ++it) {
      int i = tid + it * 256;
      int r = i >> 5, q = i & 31;
      zB[q * 32 + (((r >> 2) ^ (q & 7)) << 2) + (r & 3)] = pre[it];
    }
    if (u < 3) {                   // issue next-unit loads; fly under GEMMs
      const unsigned* zp = zs + (size_t)(i0 + (u + 1) * 512) * 1024 * zst;
#pragma unroll
      for (int it = 0; it < 4; ++it)
        pre[it] = zp[(size_t)(tid + it * 256) * zst];
    }
    __syncthreads();
#pragma unroll
    for (int nt = 0; nt < 2; ++nt) {
      int n = nt * 16 + ln;
      floatx4 pr = {0.f, 0.f, 0.f, 0.f}, pi = {0.f, 0.f, 0.f, 0.f};
#pragma unroll
      for (int t = 0; t < 2; ++t) {
        short8 b = *(const short8*)&zB[n * 32 + (((4 * t + qd) ^ (n & 7)) << 2)];
        pr = __builtin_amdgcn_mfma_f32_16x16x32_bf16(a5[t], b, pr, 0, 0, 0);
        pi = __builtin_amdgcn_mfma_f32_16x16x32_bf16(a6[t], b, pi, 0, 0, 0);
      }
#pragma unroll
      for (int j = 0; j < 4; ++j) {
        int s = wv * 16 + qd * 4 + j;
        int q = n;
        P[s * 32 + (((q >> 2) ^ (s & 7)) << 2) + (q & 3)] = pack_bf16(pr[j], pi[j]);
      }
    }
    __syncthreads();
    {
      short8 pa[2];
      int row = wv * 16 + ln;
#pragma unroll
      for (int t = 0; t < 2; ++t)
        pa[t] = *(const short8*)&P[row * 32 + (((4 * t + qd) ^ (row & 7)) << 2)];
      unsigned* ho = hsp + (size_t)blc * 4096;
#pragma unroll
      for (int nt = 0; nt < 4; ++nt) {
        int n = nt * 16 + ln;
        floatx4 hr = {0.f, 0.f, 0.f, 0.f}, hi = {0.f, 0.f, 0.f, 0.f};
#pragma unroll
        for (int t = 0; t < 2; ++t) {
          short8 b5 = *(const short8*)(rB + (0 * 64 + n) * 64 + t * 32 + qd * 8);
          short8 b6 = *(const short8*)(rB + (1 * 64 + n) * 64 + t * 32 + qd * 8);
          hr = __builtin_amdgcn_mfma_f32_16x16x32_bf16(pa[t], b5, hr, 0, 0, 0);
          hi = __builtin_amdgcn_mfma_f32_16x16x32_bf16(pa[t], b6, hi, 0, 0, 0);
        }
#pragma unroll
        for (int j = 0; j < 4; ++j) {
          int s = wv * 16 + qd * 4 + j;
          ho[s * 64 + n] = pack_bf16(hr[j], hi[j]);
        }
      }
    }
    if (u < 3) __syncthreads();    // zB/P reads done before next writes
  }
}

// --------------- MFMA 3x3 conv: 512 blocks x 2 slabs (same bl so the 36
// weight fragments load once); slab-1 interior register-prefetched under
// slab-0 LDS-write + MFMA.
__global__ __launch_bounds__(256, 2) void k_conv(
    const unsigned* __restrict__ hsp, const short* __restrict__ Wtb,
    unsigned short* __restrict__ convout, float2* __restrict__ stats) {
  __shared__ unsigned lds_in[6 * 66 * 32];   // 50,688 B
  const int bl = blockIdx.x >> 3;
  const int slab0 = blockIdx.x & 7;
  const int tid = threadIdx.x;
  const int lane = tid & 63;
  const int wv = tid >> 6;
  const int co = lane & 15;
  const int qd = lane >> 4;
  short8 bL[18], bH[18];
  {
    const short* wpL = Wtb + (co * 9) * 64 + qd * 8;
    const short* wpH = Wtb + ((co + 16) * 9) * 64 + qd * 8;
#pragma unroll
    for (int tap = 0; tap < 9; ++tap)
#pragma unroll
      for (int kk = 0; kk < 2; ++kk) {
        bL[tap * 2 + kk] = *(const short8*)(wpL + tap * 64 + kk * 32);
        bH[tap * 2 + kk] = *(const short8*)(wpH + tap * 64 + kk * 32);
      }
  }
  uint4 sv[12];
  {
    const int y0 = slab0 * 4;
#pragma unroll
    for (int t = 0; t < 12; ++t) {
      int i = t * 256 + tid;
      int ci = i & 31;
      int j = i >> 5;
      int yi = j >> 4, x4 = j & 15;
      int y = y0 + yi - 1;
      sv[t] = make_uint4(0u, 0u, 0u, 0u);
      if ((unsigned)y < 64u)
        sv[t] =
            *(const uint4*)(hsp + (((size_t)bl * 32 + ci) * 64 + y) * 64 + x4 * 4);
    }
  }
#pragma unroll
  for (int uu = 0; uu < 2; ++uu) {
    const int slab = slab0 + uu * 8;
    const int y0 = slab * 4;
    if (uu) __syncthreads();                 // prior MFMA reads done
    for (int i = tid; i < 384; i += 256) {   // zero x-border cells
      int ci = i & 31, j = i >> 5;
      int yi = j >> 1, xi = (j & 1) ? 65 : 0;
      int slot = (ci >> 2) ^ (xi & 7);
      lds_in[(yi * 66 + xi) * 32 + slot * 4 + (ci & 3)] = 0u;
    }
#pragma unroll
    for (int t = 0; t < 12; ++t) {           // interior: regs -> LDS
      int i = t * 256 + tid;
      int ci = i & 31;
      int j = i >> 5;
      int yi = j >> 4, x4 = j & 15;
      int xb = 1 + x4 * 4;
#pragma unroll
      for (int jj = 0; jj < 4; ++jj) {
        int xi = xb + jj;
        int slot = (ci >> 2) ^ (xi & 7);
        lds_in[(yi * 66 + xi) * 32 + slot * 4 + (ci & 3)] =
            ((const unsigned*)&sv[t])[jj];
      }
    }
    if (uu == 0) {                 // prefetch slab-1 interior
      const int y0n = (slab0 + 8) * 4;
#pragma unroll
      for (int t = 0; t < 12; ++t) {
        int i = t * 256 + tid;
        int ci = i & 31;
        int j = i >> 5;
        int yi = j >> 4, x4 = j & 15;
        int y = y0n + yi - 1;
        sv[t] = make_uint4(0u, 0u, 0u, 0u);
        if ((unsigned)y < 64u)
          sv[t] = *(const uint4*)(hsp +
                                  (((size_t)bl * 32 + ci) * 64 + y) * 64 + x4 * 4);
      }
    }
    __syncthreads();
    float sL = 0.f, s2L = 0.f, sH = 0.f, s2H = 0.f;
    const int x0 = wv * 16;
    const int xl = lane & 15;
    for (int ry = 0; ry < 4; ++ry) {
      floatx4 aL = {0.f, 0.f, 0.f, 0.f}, aH = {0.f, 0.f, 0.f, 0.f};
#pragma unroll
      for (int tap = 0; tap < 9; ++tap) {
        int dy = tap / 3, dx = tap - dy * 3;
        int yi = ry + dy;
        int xi = x0 + xl + dx;
#pragma unroll
        for (int kk = 0; kk < 2; ++kk) {
          int slot = ((kk << 2) | qd) ^ (xi & 7);
          const short8 a =
              *(const short8*)&lds_in[(yi * 66 + xi) * 32 + slot * 4];
          aL = __builtin_amdgcn_mfma_f32_16x16x32_bf16(a, bL[tap * 2 + kk], aL, 0, 0, 0);
          aH = __builtin_amdgcn_mfma_f32_16x16x32_bf16(a, bH[tap * 2 + kk], aH, 0, 0, 0);
        }
      }
      size_t goL = (((size_t)bl * 32 + co) * 64 + (y0 + ry)) * 64 + x0 + qd * 4;
      size_t goH = goL + (size_t)16 * 4096;
      *(uint2*)(convout + goL) =
          make_uint2(pack_bf16(aL[0], aL[1]), pack_bf16(aL[2], aL[3]));
      *(uint2*)(convout + goH) =
          make_uint2(pack_bf16(aH[0], aH[1]), pack_bf16(aH[2], aH[3]));
#pragma unroll
      for (int j = 0; j < 4; ++j) {
        sL += aL[j]; s2L += aL[j] * aL[j];
        sH += aH[j]; s2H += aH[j] * aH[j];
      }
    }
    sL += __shfl_down(sL, 32, 64);  s2L += __shfl_down(s2L, 32, 64);
    sH += __shfl_down(sH, 32, 64);  s2H += __shfl_down(s2H, 32, 64);
    sL += __shfl_down(sL, 16, 64);  s2L += __shfl_down(s2L, 16, 64);
    sH += __shfl_down(sH, 16, 64);  s2H += __shfl_down(s2H, 16, 64);
    if (lane < 16) {
      stats[((size_t)bl * 32 + lane) * 64 + slab * 4 + wv] = make_float2(sL, s2L);
      stats[((size_t)bl * 32 + 16 + lane) * 64 + slab * 4 + wv] =
          make_float2(sH, s2H);
    }
  }
}

// -------------------- LN + residual out: 1024 blocks x 2 planes (i, i+1024).
// All streaming loads issued upfront; stats for plane 0/1 reduced
// concurrently by wave 0 / wave 1; ln_w/ln_b loaded once.
__global__ __launch_bounds__(256) void k_ln(
    const unsigned short* __restrict__ convout,
    const float2* __restrict__ stats, const float* __restrict__ x,
    const float* __restrict__ ln_w, const float* __restrict__ ln_b,
    float* __restrict__ out) {
  const int tid = threadIdx.x;
  __shared__ float sh_mu[2], sh_rs[2];
  const int blc0 = blockIdx.x;
  const int blc1 = blockIdx.x + 1024;
  const float4* lwp = (const float4*)ln_w;
  const float4* lbp = (const float4*)ln_b;
  const uint2* cp0 = (const uint2*)(convout + (size_t)blc0 * 4096);
  const uint2* cp1 = (const uint2*)(convout + (size_t)blc1 * 4096);
  const float4* xp0 = (const float4*)(x + (size_t)blc0 * 4096);
  const float4* xp1 = (const float4*)(x + (size_t)blc1 * 4096);
  float4 lw[4], lb[4], xv0[4], xv1[4];
  uint2 cv0[4], cv1[4];
#pragma unroll
  for (int k = 0; k < 4; ++k) {
    int i = tid + k * 256;
    lw[k] = lwp[i];
    lb[k] = lbp[i];
    cv0[k] = cp0[i];
    xv0[k] = xp0[i];
    cv1[k] = cp1[i];
    xv1[k] = xp1[i];
  }
  const int pl = tid >> 6;
  if (pl < 2) {                    // waves 0/1 reduce plane 0/1 concurrently
    float2 v = stats[(size_t)(blockIdx.x + pl * 1024) * 64 + (tid & 63)];
    float s = v.x, s2 = v.y;
#pragma unroll
    for (int o = 32; o > 0; o >>= 1) {
      s += __shfl_down(s, o, 64);
      s2 += __shfl_down(s2, o, 64);
    }
    if ((tid & 63) == 0) {
      float mu = s * (1.f / 4096.f);
      float var = s2 * (1.f / 4096.f) - mu * mu;
      sh_mu[pl] = mu;
      sh_rs[pl] = rsqrtf(var + 1e-5f);
    }
  }
  __syncthreads();
  {
    const float mu = sh_mu[0], rs = sh_rs[0];
    float4* op = (float4*)(out + (size_t)blc0 * 4096);
#pragma unroll
    for (int k = 0; k < 4; ++k) {
      int i = tid + k * 256;
      float c0 = __uint_as_float(cv0[k].x << 16);
      float c1 = __uint_as_float(cv0[k].x & 0xFFFF0000u);
      float c2 = __uint_as_float(cv0[k].y << 16);
      float c3 = __uint_as_float(cv0[k].y & 0xFFFF0000u);
      float4 o;
      o.x = xv0[k].x + (c0 - mu) * rs * lw[k].x + lb[k].x;
      o.y = xv0[k].y + (c1 - mu) * rs * lw[k].y + lb[k].y;
      o.z = xv0[k].z + (c2 - mu) * rs * lw[k].z + lb[k].z;
      o.w = xv0[k].w + (c3 - mu) * rs * lw[k].w + lb[k].w;
      op[i] = o;
    }
  }
  {
    const float mu = sh_mu[1], rs = sh_rs[1];
    float4* op = (float4*)(out + (size_t)blc1 * 4096);
#pragma unroll
    for (int k = 0; k < 4; ++k) {
      int i = tid + k * 256;
      float c0 = __uint_as_float(cv1[k].x << 16);
      float c1 = __uint_as_float(cv1[k].x & 0xFFFF0000u);
      float c2 = __uint_as_float(cv1[k].y << 16);
      float c3 = __uint_as_float(cv1[k].y & 0xFFFF0000u);
      float4 o;
      o.x = xv1[k].x + (c0 - mu) * rs * lw[k].x + lb[k].x;
      o.y = xv1[k].y + (c1 - mu) * rs * lw[k].y + lb[k].y;
      o.z = xv1[k].z + (c2 - mu) * rs * lw[k].z + lb[k].z;
      o.w = xv1[k].w + (c3 - mu) * rs * lw[k].w + lb[k].w;
      op[i] = o;
    }
  }
}

// ------------------------------------------------------------------- launch
extern "C" void kernel_launch(void* const* d_in, const int* in_sizes, int n_in,
                              void* d_out, int out_size, void* d_ws,
                              size_t ws_size, hipStream_t stream) {
  const float* x       = (const float*)d_in[0];
  const float* listT   = (const float*)d_in[1];
  const float* plb     = (const float*)d_in[2];
  const float* dmod    = (const float*)d_in[3];
  const float* fm_W1   = (const float*)d_in[4];
  const float* fm_b1   = (const float*)d_in[5];
  const float* fm_W2   = (const float*)d_in[6];
  const float* fm_b2   = (const float*)d_in[7];
  const float* fscale  = (const float*)d_in[8];
  const float* U_re    = (const float*)d_in[9];
  const float* U_im    = (const float*)d_in[10];
  const float* V_re    = (const float*)d_in[11];
  const float* V_im    = (const float*)d_in[12];
  const float* pW_re   = (const float*)d_in[13];
  const float* pW_im   = (const float*)d_in[14];
  // d_in[15..16] pb_re/pb_im: cropped out, no effect
  const float* convr_w = (const float*)d_in[17];
  // convr_b/convi_b/projc_b (18,20,22): constant over [S,W] -> cancel in LN
  const float* convi_w = (const float*)d_in[19];
  const float* projc_w = (const float*)d_in[21];
  const float* ln_w    = (const float*)d_in[23];
  const float* ln_b    = (const float*)d_in[24];
  float* out = (float*)d_out;

  float* wsf = (float*)d_ws;
  // R0a [0, 8388608): hs (u32 packed bf16) -> later hsp (alias)
  unsigned* hs  = (unsigned*)wsf;
  unsigned* hsp = (unsigned*)wsf;
  // R0b [8388608, 16777216): coeff mats (dead before conv), then convout+stats
  unsigned* zqAp  = (unsigned*)(wsf + 8388608);           // 262144 u32
  unsigned* recAp = (unsigned*)(wsf + 8388608 + 262144);  // 131072 u32
  unsigned* recBp = (unsigned*)(wsf + 8388608 + 393216);  // 131072 u32
  unsigned short* convout = (unsigned short*)(wsf + 8388608);  // 8388608 u16
  float2*   stats = (float2*)(wsf + 12582912);            // 131072 float2
  float2*   zq  = (float2*)(wsf + 16777216);              // 4,194,304 fl
  size_t off = 16777216 + 4194304;
  // zs: packed bf16 u32; separate region if ws allows, else overlaid on zq.
  const size_t tail = 238592;  // lam+gam+ctxp+Wtb
  unsigned* zs;
  int zst;
  size_t off2;
  if (ws_size >= (off + 2097152 + tail) * 4) {
    zs = (unsigned*)(wsf + off); zst = 1; off2 = off + 2097152;
  } else {
    zs = (unsigned*)zq; zst = 2; off2 = off;
  }
  float2*   lam  = (float2*)(wsf + off2);                 // 131,072 fl
  float*    gam  = wsf + off2 + 131072;                   // 65,536 fl
  float*    ctxp = wsf + off2 + 196608;                   // 32,768 fl
  unsigned* Wtb  = (unsigned*)(wsf + off2 + 229376);      // 9,216 u32

  k_mixprep<<<612, 256, 0, stream>>>(x, pW_re, pW_im, U_re, U_im, V_re, V_im,
                                     projc_w, convr_w, convi_w, hs, ctxp,
                                     zqAp, recAp, recBp, Wtb);
  k_zq<<<576, 256, 0, stream>>>(hs, (const short*)zqAp, zq, ctxp, listT, plb,
                                dmod, fm_W1, fm_b1, fm_W2, fm_b2, fscale,
                                lam, gam);
  k_scan<<<1024, 256, 0, stream>>>(lam, gam, zq, zs, zst);
  k_rec<<<512, 256, 0, stream>>>(zs, zst, (const short*)recAp,
                                 (const short*)recBp, hsp);
  k_conv<<<512, 256, 0, stream>>>(hsp, (const short*)Wtb, convout, stats);
  k_ln<<<1024, 256, 0, stream>>>(convout, stats, x, ln_w, ln_b, out);
}

// Round 10
// 232.303 us; speedup vs baseline: 1.0290x; 1.0290x over previous
//
#include <hip/hip_runtime.h>

// Dims: B=2, L=32, C=32, S=64, W=64, R=32, MH=32. BL=64, SW=4096.
//
// 6-dispatch pipeline, all bodies software-pipelined (prefetch-under-compute,
// NO cross-block sync):
//  k_mixprep: mix 2 segs/block + DFT coeff mats + weff
//  k_zq:      4 (bl,c) units/block (same c -> coeffs loaded once) + MLP tail
//  k_scan:    4-way split-chain scan, bf16-packed output
//  k_rec:     4 units/block (same c), rec GEMMs -> hsp
//  k_conv:    2 slabs/block (same bl -> weights loaded once; R7-proven body,
//             NO long-lived register prefetch -- that regressed in R8)
//  k_ln:      2 planes/block, parallel stats reduce in waves 0/1

typedef __attribute__((ext_vector_type(8))) short short8;
typedef __attribute__((ext_vector_type(4))) float floatx4;

__device__ __forceinline__ unsigned pack_bf16(float re, float im) {
  unsigned a = __float_as_uint(re), b = __float_as_uint(im);
  a = (a + 0x7FFFu + ((a >> 16) & 1u)) >> 16;
  b = (b + 0x7FFFu + ((b >> 16) & 1u)) >> 16;
  return a | (b << 16);
}
__device__ __forceinline__ unsigned short bf16r(float v) {
  unsigned a = __float_as_uint(v);
  return (unsigned short)((a + 0x7FFFu + ((a >> 16) & 1u)) >> 16);
}

// ------------------------------------------------------------- k_mixprep
// mix: blocks 0..511 (2 segments each, seg-1 x prefetched under seg-0);
// DFT: 512..575; weff: 576..611.
__global__ __launch_bounds__(256) void k_mixprep(
    const float* __restrict__ x, const float* __restrict__ pWr,
    const float* __restrict__ pWi,
    const float* __restrict__ U_re, const float* __restrict__ U_im,
    const float* __restrict__ V_re, const float* __restrict__ V_im,
    const float* __restrict__ projc_w, const float* __restrict__ convr_w,
    const float* __restrict__ convi_w,
    unsigned* __restrict__ hs, float* __restrict__ ctxp,
    unsigned* __restrict__ zqA, unsigned* __restrict__ recA,
    unsigned* __restrict__ recB, unsigned* __restrict__ Wtb) {
  __shared__ __align__(16) char smem[33280];
  const int tid = threadIdx.x;
  if (blockIdx.x < 512) {                     // ---------------- mix body
    unsigned* xb_s = (unsigned*)smem;                       // [256*20] 20 KB
    float(*red)[16][2] = (float(*)[16][2])(smem + 20480);   // [16][16][2] 2 KB
    unsigned* outb = (unsigned*)smem;                       // [32][260] 33 KB
    const int bl = blockIdx.x >> 3;
    const int seg0 = blockIdx.x & 7;
    const int lane = tid & 63, wv = tid >> 6;
    const int qd = lane >> 4, ln = lane & 15;
    short8 arL, aiL, arH, aiH;
#pragma unroll
    for (int j = 0; j < 8; ++j) {
      int ci = qd * 8 + j;
      ((short*)&arL)[j] = (short)bf16r(pWr[ci * 32 + ln]);
      ((short*)&aiL)[j] = (short)bf16r(pWi[ci * 32 + ln]);
      ((short*)&arH)[j] = (short)bf16r(pWr[ci * 32 + 16 + ln]);
      ((short*)&aiH)[j] = (short)bf16r(pWi[ci * 32 + 16 + ln]);
    }
    float4 pa[4], pb[4];
    {
      const float* xb = x + (size_t)bl * 131072 + seg0 * 256;
#pragma unroll
      for (int t = 0; t < 4; ++t) {
        int i = t * 256 + tid;
        int c2 = i & 15, g4 = i >> 4;
        pa[t] = *(const float4*)(xb + (2 * c2) * 4096 + g4 * 4);
        pb[t] = *(const float4*)(xb + (2 * c2 + 1) * 4096 + g4 * 4);
      }
    }
#pragma unroll
    for (int u = 0; u < 2; ++u) {
      const int seg = seg0 + u * 8;
      const int pxbase = seg * 256;
      if (u) __syncthreads();       // prior hs-store outb reads complete
      float csa = 0.f, csb = 0.f;
#pragma unroll
      for (int t = 0; t < 4; ++t) {
        int i = t * 256 + tid;
        int c2 = i & 15, g4 = i >> 4;
        float4 a = pa[t], b = pb[t];
        csa += a.x + a.y + a.z + a.w;
        csb += b.x + b.y + b.z + b.w;
#pragma unroll
        for (int j = 0; j < 4; ++j) {
          int px = g4 * 4 + j;
          xb_s[px * 20 + (((c2 >> 2) ^ (px & 3)) << 2) + (c2 & 3)] =
              pack_bf16(((const float*)&a)[j], ((const float*)&b)[j]);
        }
      }
      red[tid & 15][tid >> 4][0] = csa;
      red[tid & 15][tid >> 4][1] = csb;
      if (u == 0) {                 // prefetch seg1 x under this seg's work
        const float* xb1 = x + (size_t)bl * 131072 + (seg0 + 8) * 256;
#pragma unroll
        for (int t = 0; t < 4; ++t) {
          int i = t * 256 + tid;
          int c2 = i & 15, g4 = i >> 4;
          pa[t] = *(const float4*)(xb1 + (2 * c2) * 4096 + g4 * 4);
          pb[t] = *(const float4*)(xb1 + (2 * c2 + 1) * 4096 + g4 * 4);
        }
      }
      __syncthreads();
      if (tid < 32) {               // ctx partial for this (bl, seg)
        int c2 = tid >> 1, part = tid & 1;
        float s = 0.f;
#pragma unroll
        for (int w = 0; w < 16; ++w) s += red[c2][w][part];
        ctxp[(bl * 16 + seg) * 32 + 2 * c2 + part] = s;
      }
      floatx4 RL[4], IL[4], RH[4], IH[4];
#pragma unroll
      for (int pt = 0; pt < 4; ++pt) {
        int pxt = wv * 4 + pt;
        int pxl = pxt * 16 + ln;
        short8 bfr = *(const short8*)&xb_s[pxl * 20 + ((qd ^ (pxl & 3)) << 2)];
        floatx4 z4 = {0.f, 0.f, 0.f, 0.f};
        RL[pt] = __builtin_amdgcn_mfma_f32_16x16x32_bf16(arL, bfr, z4, 0, 0, 0);
        IL[pt] = __builtin_amdgcn_mfma_f32_16x16x32_bf16(aiL, bfr, z4, 0, 0, 0);
        RH[pt] = __builtin_amdgcn_mfma_f32_16x16x32_bf16(arH, bfr, z4, 0, 0, 0);
        IH[pt] = __builtin_amdgcn_mfma_f32_16x16x32_bf16(aiH, bfr, z4, 0, 0, 0);
      }
      __syncthreads();              // xb_s dead; reuse as outb
#pragma unroll
      for (int pt = 0; pt < 4; ++pt) {
        int px = (wv * 4 + pt) * 16 + ln;
#pragma unroll
        for (int j = 0; j < 4; ++j) {
          outb[(qd * 4 + j) * 260 + px] = pack_bf16(RL[pt][j], IL[pt][j]);
          outb[(16 + qd * 4 + j) * 260 + px] = pack_bf16(RH[pt][j], IH[pt][j]);
        }
      }
      __syncthreads();
      unsigned* ho = hs + (size_t)bl * 131072 + pxbase;
      const int px4 = tid & 63, dg = tid >> 6;
#pragma unroll
      for (int dd = 0; dd < 8; ++dd) {
        int d = dg * 8 + dd;
        uint4 v = *(const uint4*)&outb[d * 260 + px4 * 4];
        *(uint4*)(ho + d * 4096 + px4 * 4) = v;
      }
    }
  } else if (blockIdx.x < 576) {              // ---------------- DFT body
    float2* A2 = (float2*)smem;               // [2048] 16 KB
    float2* tw = (float2*)(smem + 16384);     // [64]
    const int id = blockIdx.x - 512;
    const int c = id >> 1, src = id & 1;      // 0=U(plus), 1=V(minus)
    const float* Ar = (src ? V_re : U_re) + c * 2048;
    const float* Ai = (src ? V_im : U_im) + c * 2048;
    if (tid < 64) {
      float sa, ca;
      sincosf((float)tid * 0.09817477042468103f, &sa, &ca);
      tw[tid] = make_float2(ca, sa);
    }
#pragma unroll
    for (int t = 0; t < 8; ++t) {
      int idx = t * 256 + tid;
      A2[idx] = make_float2(Ar[idx], Ai[idx]);
    }
    __syncthreads();
    const int kw = tid >> 2, mg = tid & 3;
    float sr[8] = {0.f, 0.f, 0.f, 0.f, 0.f, 0.f, 0.f, 0.f};
    float si[8] = {0.f, 0.f, 0.f, 0.f, 0.f, 0.f, 0.f, 0.f};
#pragma unroll 4
    for (int n = 0; n < 64; ++n) {
      float2 w = tw[(kw * n) & 63];
      float ws = src ? -w.y : w.y;
#pragma unroll
      for (int t4 = 0; t4 < 4; ++t4) {
        float4 q = *(const float4*)&A2[n * 32 + mg * 8 + t4 * 2];
        sr[2 * t4]     += q.x * w.x - q.y * ws;
        si[2 * t4]     += q.x * ws + q.y * w.x;
        sr[2 * t4 + 1] += q.z * w.x - q.w * ws;
        si[2 * t4 + 1] += q.z * ws + q.w * w.x;
      }
    }
#pragma unroll
    for (int j = 0; j < 8; ++j) {
      float r = sr[j] * 0.125f, i2 = si[j] * 0.125f;
      int m = mg * 8 + j;
      unsigned p_ri  = pack_bf16(r, i2);
      unsigned p_rmi = pack_bf16(r, -i2);
      unsigned p_ir  = pack_bf16(i2, r);
      unsigned p_mir = pack_bf16(-i2, r);
      if (src == 0) {                         // F+ . U
        zqA[((c * 4 + 2) * 32 + m) * 64 + kw] = p_ri;   // A3
        zqA[((c * 4 + 3) * 32 + m) * 64 + kw] = p_mir;  // A4
        recA[((c * 2 + 0) * 64 + kw) * 32 + m] = p_rmi; // A5
        recA[((c * 2 + 1) * 64 + kw) * 32 + m] = p_ir;  // A6
      } else {                                // F- . V
        zqA[((c * 4 + 0) * 32 + m) * 64 + kw] = p_rmi;  // A1
        zqA[((c * 4 + 1) * 32 + m) * 64 + kw] = p_ir;   // A2
        recB[((c * 2 + 0) * 64 + kw) * 32 + m] = p_ri;  // B5
        recB[((c * 2 + 1) * 64 + kw) * 32 + m] = p_mir; // B6
      }
    }
  } else {                                    // ---------------- weff body
    int gid = (blockIdx.x - 576) * 256 + tid;   // (co*9+tap)*32 + ci
    if (gid < 9216) {
      int co = gid / 288;
      int r2 = gid - co * 288;
      int tap = r2 >> 5, ci = r2 & 31;
      float sr = 0.f, si = 0.f;
      for (int m = 0; m < 32; ++m) {
        sr += projc_w[co * 64 + m]      * convr_w[(m * 32 + ci) * 9 + tap];
        si += projc_w[co * 64 + 32 + m] * convi_w[(m * 32 + ci) * 9 + tap];
      }
      Wtb[gid] = pack_bf16(sr, si);
    }
  }
}

// --------------- MFMA zq: 512 blocks x 4 units (i0+512u; same c so coeff
// fragments load once; unit u+1 hs loads issued before unit-u GEMMs) +
// 64 MLP tail blocks (512..575).
__global__ __launch_bounds__(256) void k_zq(
    const unsigned* __restrict__ hs, const short* __restrict__ zqA,
    float2* __restrict__ zq,
    const float* __restrict__ ctxp, const float* __restrict__ listT,
    const float* __restrict__ plb, const float* __restrict__ dmod,
    const float* __restrict__ W1, const float* __restrict__ b1,
    const float* __restrict__ W2, const float* __restrict__ b2,
    const float* __restrict__ fscale,
    float2* __restrict__ lam, float* __restrict__ gam) {
  __shared__ unsigned HsB[4096];   // [s][w-chunks xor-swizzled], 16 KB
  __shared__ unsigned T2[2048];    // [q][s-chunks xor-swizzled], 8 KB
  __shared__ float mid_s[32];
  __shared__ float ctxs[32];
  const int tid = threadIdx.x;
  if (blockIdx.x >= 512) {         // ---- MLP -> lam/gam (ctx ready: mix done)
    int bl = blockIdx.x - 512;
    float dt = listT[bl];
    if (tid < 32) {                // sum the 16 per-segment ctx partials
      float s = 0.f;
#pragma unroll
      for (int sg = 0; sg < 16; ++sg) s += ctxp[(bl * 16 + sg) * 32 + tid];
      ctxs[tid] = s * (1.f / 4096.f);
    }
    __syncthreads();
    if (tid < 32) {
      float a = b1[tid];
      for (int j = 0; j < 32; ++j) a += ctxs[j] * W1[j * 32 + tid];
      a += dt * W1[1024 + tid];
      mid_s[tid] = tanhf(a);
    }
    __syncthreads();
    float fs = fscale[0];
#pragma unroll
    for (int u = 0; u < 4; ++u) {
      int cr = u * 256 + tid;
      int col = cr * 2;
      float m0 = b2[col], m1 = b2[col + 1];
      for (int h = 0; h < 32; ++h) {
        float mh = mid_s[h];
        float2 w2 = *(const float2*)&W2[h * 2048 + col];
        m0 += mh * w2.x;
        m1 += mh * w2.y;
      }
      float dnu = fs * tanhf(m0);
      float dth = fs * tanhf(m1);
      float nub = expf(plb[cr] + dmod[cr]);
      float thb = expf(plb[1024 + cr] + dmod[1024 + cr]);
      float nut = fmaxf(nub * dt + dnu, 1e-6f);
      float tht = thb * dt + dth;
      float e = expf(-nut);
      float sa, ca;
      sincosf(tht, &sa, &ca);
      float g = sqrtf(fmaxf(1.f - expf(-2.f * nut), 1e-12f));
      int o = bl * 1024 + cr;
      lam[o] = make_float2(e * ca, e * sa);
      gam[o] = g;
    }
    return;
  }
  const int i0 = blockIdx.x;
  const int c = i0 & 31;
  const int lane = tid & 63, wv = tid >> 6;
  const int qd = lane >> 4, ln = lane & 15;
  const int mt = wv >> 1, nth = wv & 1;
  const short* zA = zqA + (size_t)c * 4 * 32 * 128;
  short8 a1[4], a2[4], a3[4], a4[4];
#pragma unroll
  for (int t = 0; t < 4; ++t) {
    int row = mt * 16 + ln;
    a1[t] = *(const short8*)(zA + (0 * 32 + row) * 128 + t * 32 + qd * 8);
    a2[t] = *(const short8*)(zA + (1 * 32 + row) * 128 + t * 32 + qd * 8);
    a3[t] = *(const short8*)(zA + (2 * 32 + row) * 128 + t * 32 + qd * 8);
    a4[t] = *(const short8*)(zA + (3 * 32 + row) * 128 + t * 32 + qd * 8);
  }
  uint4 pre[4];
  {
    const uint4* hp = (const uint4*)(hs + (size_t)i0 * 4096);
#pragma unroll
    for (int it = 0; it < 4; ++it) pre[it] = hp[tid + it * 256];
  }
#pragma unroll
  for (int u = 0; u < 4; ++u) {
    const int blc = i0 + u * 512;
#pragma unroll
    for (int it = 0; it < 4; ++it) {
      int i4 = tid + it * 256;
      int s = i4 >> 4, w4 = i4 & 15;
      *(uint4*)&HsB[s * 64 + ((w4 ^ (s & 15)) << 2)] = pre[it];
    }
    if (u < 3) {                   // issue next-unit loads; fly under GEMMs
      const uint4* hp = (const uint4*)(hs + (size_t)(i0 + (u + 1) * 512) * 4096);
#pragma unroll
      for (int it = 0; it < 4; ++it) pre[it] = hp[tid + it * 256];
    }
    __syncthreads();
#pragma unroll
    for (int nti = 0; nti < 2; ++nti) {
      int nt = nth * 2 + nti;
      int n = nt * 16 + ln;
      floatx4 accr = {0.f, 0.f, 0.f, 0.f}, acci = {0.f, 0.f, 0.f, 0.f};
#pragma unroll
      for (int t = 0; t < 4; ++t) {
        short8 b = *(const short8*)&HsB[n * 64 + (((4 * t + qd) ^ (n & 15)) << 2)];
        accr = __builtin_amdgcn_mfma_f32_16x16x32_bf16(a1[t], b, accr, 0, 0, 0);
        acci = __builtin_amdgcn_mfma_f32_16x16x32_bf16(a2[t], b, acci, 0, 0, 0);
      }
#pragma unroll
      for (int j = 0; j < 4; ++j) {
        int q = mt * 16 + qd * 4 + j;
        int s = n;
        T2[q * 64 + (((s >> 2) ^ (q & 15)) << 2) + (s & 3)] =
            pack_bf16(accr[j], acci[j]);
      }
    }
    __syncthreads();
    {
      const int mt2 = wv >> 1, nt2 = wv & 1;
      int n = nt2 * 16 + ln;
      floatx4 zr = {0.f, 0.f, 0.f, 0.f}, zi = {0.f, 0.f, 0.f, 0.f};
#pragma unroll
      for (int t = 0; t < 4; ++t) {
        short8 b = *(const short8*)&T2[n * 64 + (((4 * t + qd) ^ (n & 15)) << 2)];
        zr = __builtin_amdgcn_mfma_f32_16x16x32_bf16(a3[t], b, zr, 0, 0, 0);
        zi = __builtin_amdgcn_mfma_f32_16x16x32_bf16(a4[t], b, zi, 0, 0, 0);
      }
      float2* zo = zq + (size_t)blc * 1024;
#pragma unroll
      for (int j = 0; j < 4; ++j) {
        int r = mt2 * 16 + qd * 4 + j;
        zo[r * 32 + n] = make_float2(zr[j], zi[j]);
      }
    }
    if (u < 3) __syncthreads();    // T2/HsB reads done before next writes
  }
}

// --------------------- linear scan: 4-way split chains + LDS carry fixup.
__global__ __launch_bounds__(256) void k_scan(const float2* __restrict__ lam,
                                              const float* __restrict__ gam,
                                              const float2* __restrict__ zin,
                                              unsigned* __restrict__ zsp,
                                              int zst) {
  __shared__ float2 se[4][64];
  __shared__ float2 pe[4][64];
  __shared__ float2 cr_s[4][64];
  const int bc = blockIdx.x >> 4;            // b*32 + c
  const int b = bc >> 5, c = bc & 31;
  const int rq0 = (blockIdx.x & 15) * 64;
  const int seg = threadIdx.x >> 6, u = threadIdx.x & 63;
  const int rq = rq0 + u, r = rq >> 5;
  const int t0 = seg * 8;
  float2 vv[8], ll[8];
  float gg[8];
#pragma unroll
  for (int i = 0; i < 8; ++i) {              // independent loads, all in flight
    int t = b * 32 + t0 + i;
    vv[i] = zin[((size_t)t * 32 + c) * 1024 + rq];
    ll[i] = lam[t * 1024 + c * 32 + r];
    gg[i] = gam[t * 1024 + c * 32 + r];
  }
  float2 s = make_float2(0.f, 0.f), P = make_float2(1.f, 0.f);
  float2 zloc[8], Ps[8];
#pragma unroll
  for (int i = 0; i < 8; ++i) {
    float2 lm = ll[i];
    float nr = lm.x * s.x - lm.y * s.y + gg[i] * vv[i].x;
    float ni = lm.x * s.y + lm.y * s.x + gg[i] * vv[i].y;
    s = make_float2(nr, ni);
    float pr = P.x * lm.x - P.y * lm.y;
    float pi = P.x * lm.y + P.y * lm.x;
    P = make_float2(pr, pi);
    zloc[i] = s;
    Ps[i] = P;
  }
  se[seg][u] = s;
  pe[seg][u] = P;
  __syncthreads();
  if (threadIdx.x < 64) {                    // per-chain carry combine
    float2 c1 = se[0][u];
    float2 p1 = pe[1][u], s1 = se[1][u];
    float2 c2 = make_float2(s1.x + p1.x * c1.x - p1.y * c1.y,
                            s1.y + p1.x * c1.y + p1.y * c1.x);
    float2 p2 = pe[2][u], s2 = se[2][u];
    float2 c3 = make_float2(s2.x + p2.x * c2.x - p2.y * c2.y,
                            s2.y + p2.x * c2.y + p2.y * c2.x);
    cr_s[0][u] = make_float2(0.f, 0.f);
    cr_s[1][u] = c1;
    cr_s[2][u] = c2;
    cr_s[3][u] = c3;
  }
  __syncthreads();
  float2 cr = cr_s[seg][u];
#pragma unroll
  for (int i = 0; i < 8; ++i) {
    float zr = zloc[i].x + Ps[i].x * cr.x - Ps[i].y * cr.y;
    float zi = zloc[i].y + Ps[i].x * cr.y + Ps[i].y * cr.x;
    size_t idx = ((size_t)(b * 32 + t0 + i) * 32 + c) * 1024 + rq;
    zsp[idx * zst] = pack_bf16(zr, zi);
  }
}

// --------------- MFMA rec: 512 blocks x 4 units (i0+512u; same c so recA
// fragments load once; next-unit zs loads fly under current GEMMs).
__global__ __launch_bounds__(256) void k_rec(const unsigned* __restrict__ zs,
                                             int zst,
                                             const short* __restrict__ recA,
                                             const short* __restrict__ recB,
                                             unsigned* __restrict__ hsp) {
  __shared__ unsigned zB[1024];
  __shared__ unsigned P[2048];
  const int i0 = blockIdx.x;
  const int c = i0 & 31;
  const int tid = threadIdx.x;
  const int lane = tid & 63, wv = tid >> 6;
  const int qd = lane >> 4, ln = lane & 15;
  const short* rA = recA + (size_t)c * 2 * 64 * 64;
  short8 a5[2], a6[2];
#pragma unroll
  for (int t = 0; t < 2; ++t) {
    int row = wv * 16 + ln;
    a5[t] = *(const short8*)(rA + (0 * 64 + row) * 64 + t * 32 + qd * 8);
    a6[t] = *(const short8*)(rA + (1 * 64 + row) * 64 + t * 32 + qd * 8);
  }
  const short* rB = recB + (size_t)c * 2 * 64 * 64;
  unsigned pre[4];
  {
    const unsigned* zp = zs + (size_t)i0 * 1024 * zst;
#pragma unroll
    for (int it = 0; it < 4; ++it)
      pre[it] = zp[(size_t)(tid + it * 256) * zst];
  }
#pragma unroll
  for (int u = 0; u < 4; ++u) {
    const int blc = i0 + u * 512;
#pragma unroll
    for (int it = 0; it < 4; ++it) {
      int i = tid + it * 256;
      int r = i >> 5, q = i & 31;
      zB[q * 32 + (((r >> 2) ^ (q & 7)) << 2) + (r & 3)] = pre[it];
    }
    if (u < 3) {                   // issue next-unit loads; fly under GEMMs
      const unsigned* zp = zs + (size_t)(i0 + (u + 1) * 512) * 1024 * zst;
#pragma unroll
      for (int it = 0; it < 4; ++it)
        pre[it] = zp[(size_t)(tid + it * 256) * zst];
    }
    __syncthreads();
#pragma unroll
    for (int nt = 0; nt < 2; ++nt) {
      int n = nt * 16 + ln;
      floatx4 pr = {0.f, 0.f, 0.f, 0.f}, pi = {0.f, 0.f, 0.f, 0.f};
#pragma unroll
      for (int t = 0; t < 2; ++t) {
        short8 b = *(const short8*)&zB[n * 32 + (((4 * t + qd) ^ (n & 7)) << 2)];
        pr = __builtin_amdgcn_mfma_f32_16x16x32_bf16(a5[t], b, pr, 0, 0, 0);
        pi = __builtin_amdgcn_mfma_f32_16x16x32_bf16(a6[t], b, pi, 0, 0, 0);
      }
#pragma unroll
      for (int j = 0; j < 4; ++j) {
        int s = wv * 16 + qd * 4 + j;
        int q = n;
        P[s * 32 + (((q >> 2) ^ (s & 7)) << 2) + (q & 3)] = pack_bf16(pr[j], pi[j]);
      }
    }
    __syncthreads();
    {
      short8 pa[2];
      int row = wv * 16 + ln;
#pragma unroll
      for (int t = 0; t < 2; ++t)
        pa[t] = *(const short8*)&P[row * 32 + (((4 * t + qd) ^ (row & 7)) << 2)];
      unsigned* ho = hsp + (size_t)blc * 4096;
#pragma unroll
      for (int nt = 0; nt < 4; ++nt) {
        int n = nt * 16 + ln;
        floatx4 hr = {0.f, 0.f, 0.f, 0.f}, hi = {0.f, 0.f, 0.f, 0.f};
#pragma unroll
        for (int t = 0; t < 2; ++t) {
          short8 b5 = *(const short8*)(rB + (0 * 64 + n) * 64 + t * 32 + qd * 8);
          short8 b6 = *(const short8*)(rB + (1 * 64 + n) * 64 + t * 32 + qd * 8);
          hr = __builtin_amdgcn_mfma_f32_16x16x32_bf16(pa[t], b5, hr, 0, 0, 0);
          hi = __builtin_amdgcn_mfma_f32_16x16x32_bf16(pa[t], b6, hi, 0, 0, 0);
        }
#pragma unroll
        for (int j = 0; j < 4; ++j) {
          int s = wv * 16 + qd * 4 + j;
          ho[s * 64 + n] = pack_bf16(hr[j], hi[j]);
        }
      }
    }
    if (u < 3) __syncthreads();    // zB/P reads done before next writes
  }
}

// --------------- MFMA 3x3 conv: 512 blocks x 2 slabs (same bl so the 36
// weight fragments load once per block). R7-proven body: slab-1 restaged
// from global after a barrier (no long-lived register prefetch).
__global__ __launch_bounds__(256, 2) void k_conv(
    const unsigned* __restrict__ hsp, const short* __restrict__ Wtb,
    unsigned short* __restrict__ convout, float2* __restrict__ stats) {
  __shared__ unsigned lds_in[6 * 66 * 32];   // 50,688 B
  const int bl = blockIdx.x >> 3;
  const int slab0 = blockIdx.x & 7;
  const int tid = threadIdx.x;
  const int lane = tid & 63;
  const int wv = tid >> 6;
  const int co = lane & 15;
  const int qd = lane >> 4;
  short8 bL[18], bH[18];
  {
    const short* wpL = Wtb + (co * 9) * 64 + qd * 8;
    const short* wpH = Wtb + ((co + 16) * 9) * 64 + qd * 8;
#pragma unroll
    for (int tap = 0; tap < 9; ++tap)
#pragma unroll
      for (int kk = 0; kk < 2; ++kk) {
        bL[tap * 2 + kk] = *(const short8*)(wpL + tap * 64 + kk * 32);
        bH[tap * 2 + kk] = *(const short8*)(wpH + tap * 64 + kk * 32);
      }
  }
#pragma unroll
  for (int uu = 0; uu < 2; ++uu) {
    const int slab = slab0 + uu * 8;
    const int y0 = slab * 4;
    if (uu) __syncthreads();                 // prior MFMA reads done
    for (int i = tid; i < 384; i += 256) {   // zero x-border cells
      int ci = i & 31, j = i >> 5;
      int yi = j >> 1, xi = (j & 1) ? 65 : 0;
      int slot = (ci >> 2) ^ (xi & 7);
      lds_in[(yi * 66 + xi) * 32 + slot * 4 + (ci & 3)] = 0u;
    }
#pragma unroll
    for (int t = 0; t < 12; ++t) {           // interior staging
      int i = t * 256 + tid;
      int ci = i & 31;
      int j = i >> 5;
      int yi = j >> 4, x4 = j & 15;
      int y = y0 + yi - 1;
      uint4 v = make_uint4(0u, 0u, 0u, 0u);
      if ((unsigned)y < 64u)
        v = *(const uint4*)(hsp + (((size_t)bl * 32 + ci) * 64 + y) * 64 + x4 * 4);
      int xb = 1 + x4 * 4;
#pragma unroll
      for (int jj = 0; jj < 4; ++jj) {
        int xi = xb + jj;
        int slot = (ci >> 2) ^ (xi & 7);
        lds_in[(yi * 66 + xi) * 32 + slot * 4 + (ci & 3)] =
            ((const unsigned*)&v)[jj];
      }
    }
    __syncthreads();
    float sL = 0.f, s2L = 0.f, sH = 0.f, s2H = 0.f;
    const int x0 = wv * 16;
    const int xl = lane & 15;
    for (int ry = 0; ry < 4; ++ry) {
      floatx4 aL = {0.f, 0.f, 0.f, 0.f}, aH = {0.f, 0.f, 0.f, 0.f};
#pragma unroll
      for (int tap = 0; tap < 9; ++tap) {
        int dy = tap / 3, dx = tap - dy * 3;
        int yi = ry + dy;
        int xi = x0 + xl + dx;
#pragma unroll
        for (int kk = 0; kk < 2; ++kk) {
          int slot = ((kk << 2) | qd) ^ (xi & 7);
          const short8 a =
              *(const short8*)&lds_in[(yi * 66 + xi) * 32 + slot * 4];
          aL = __builtin_amdgcn_mfma_f32_16x16x32_bf16(a, bL[tap * 2 + kk], aL, 0, 0, 0);
          aH = __builtin_amdgcn_mfma_f32_16x16x32_bf16(a, bH[tap * 2 + kk], aH, 0, 0, 0);
        }
      }
      size_t goL = (((size_t)bl * 32 + co) * 64 + (y0 + ry)) * 64 + x0 + qd * 4;
      size_t goH = goL + (size_t)16 * 4096;
      *(uint2*)(convout + goL) =
          make_uint2(pack_bf16(aL[0], aL[1]), pack_bf16(aL[2], aL[3]));
      *(uint2*)(convout + goH) =
          make_uint2(pack_bf16(aH[0], aH[1]), pack_bf16(aH[2], aH[3]));
#pragma unroll
      for (int j = 0; j < 4; ++j) {
        sL += aL[j]; s2L += aL[j] * aL[j];
        sH += aH[j]; s2H += aH[j] * aH[j];
      }
    }
    sL += __shfl_down(sL, 32, 64);  s2L += __shfl_down(s2L, 32, 64);
    sH += __shfl_down(sH, 32, 64);  s2H += __shfl_down(s2H, 32, 64);
    sL += __shfl_down(sL, 16, 64);  s2L += __shfl_down(s2L, 16, 64);
    sH += __shfl_down(sH, 16, 64);  s2H += __shfl_down(s2H, 16, 64);
    if (lane < 16) {
      stats[((size_t)bl * 32 + lane) * 64 + slab * 4 + wv] = make_float2(sL, s2L);
      stats[((size_t)bl * 32 + 16 + lane) * 64 + slab * 4 + wv] =
          make_float2(sH, s2H);
    }
  }
}

// -------------------- LN + residual out: 1024 blocks x 2 planes (i, i+1024).
// All streaming loads issued upfront; stats for plane 0/1 reduced
// concurrently by wave 0 / wave 1; ln_w/ln_b loaded once.
__global__ __launch_bounds__(256) void k_ln(
    const unsigned short* __restrict__ convout,
    const float2* __restrict__ stats, const float* __restrict__ x,
    const float* __restrict__ ln_w, const float* __restrict__ ln_b,
    float* __restrict__ out) {
  const int tid = threadIdx.x;
  __shared__ float sh_mu[2], sh_rs[2];
  const int blc0 = blockIdx.x;
  const int blc1 = blockIdx.x + 1024;
  const float4* lwp = (const float4*)ln_w;
  const float4* lbp = (const float4*)ln_b;
  const uint2* cp0 = (const uint2*)(convout + (size_t)blc0 * 4096);
  const uint2* cp1 = (const uint2*)(convout + (size_t)blc1 * 4096);
  const float4* xp0 = (const float4*)(x + (size_t)blc0 * 4096);
  const float4* xp1 = (const float4*)(x + (size_t)blc1 * 4096);
  float4 lw[4], lb[4], xv0[4], xv1[4];
  uint2 cv0[4], cv1[4];
#pragma unroll
  for (int k = 0; k < 4; ++k) {
    int i = tid + k * 256;
    lw[k] = lwp[i];
    lb[k] = lbp[i];
    cv0[k] = cp0[i];
    xv0[k] = xp0[i];
    cv1[k] = cp1[i];
    xv1[k] = xp1[i];
  }
  const int pl = tid >> 6;
  if (pl < 2) {                    // waves 0/1 reduce plane 0/1 concurrently
    float2 v = stats[(size_t)(blockIdx.x + pl * 1024) * 64 + (tid & 63)];
    float s = v.x, s2 = v.y;
#pragma unroll
    for (int o = 32; o > 0; o >>= 1) {
      s += __shfl_down(s, o, 64);
      s2 += __shfl_down(s2, o, 64);
    }
    if ((tid & 63) == 0) {
      float mu = s * (1.f / 4096.f);
      float var = s2 * (1.f / 4096.f) - mu * mu;
      sh_mu[pl] = mu;
      sh_rs[pl] = rsqrtf(var + 1e-5f);
    }
  }
  __syncthreads();
  {
    const float mu = sh_mu[0], rs = sh_rs[0];
    float4* op = (float4*)(out + (size_t)blc0 * 4096);
#pragma unroll
    for (int k = 0; k < 4; ++k) {
      int i = tid + k * 256;
      float c0 = __uint_as_float(cv0[k].x << 16);
      float c1 = __uint_as_float(cv0[k].x & 0xFFFF0000u);
      float c2 = __uint_as_float(cv0[k].y << 16);
      float c3 = __uint_as_float(cv0[k].y & 0xFFFF0000u);
      float4 o;
      o.x = xv0[k].x + (c0 - mu) * rs * lw[k].x + lb[k].x;
      o.y = xv0[k].y + (c1 - mu) * rs * lw[k].y + lb[k].y;
      o.z = xv0[k].z + (c2 - mu) * rs * lw[k].z + lb[k].z;
      o.w = xv0[k].w + (c3 - mu) * rs * lw[k].w + lb[k].w;
      op[i] = o;
    }
  }
  {
    const float mu = sh_mu[1], rs = sh_rs[1];
    float4* op = (float4*)(out + (size_t)blc1 * 4096);
#pragma unroll
    for (int k = 0; k < 4; ++k) {
      int i = tid + k * 256;
      float c0 = __uint_as_float(cv1[k].x << 16);
      float c1 = __uint_as_float(cv1[k].x & 0xFFFF0000u);
      float c2 = __uint_as_float(cv1[k].y << 16);
      float c3 = __uint_as_float(cv1[k].y & 0xFFFF0000u);
      float4 o;
      o.x = xv1[k].x + (c0 - mu) * rs * lw[k].x + lb[k].x;
      o.y = xv1[k].y + (c1 - mu) * rs * lw[k].y + lb[k].y;
      o.z = xv1[k].z + (c2 - mu) * rs * lw[k].z + lb[k].z;
      o.w = xv1[k].w + (c3 - mu) * rs * lw[k].w + lb[k].w;
      op[i] = o;
    }
  }
}

// ------------------------------------------------------------------- launch
extern "C" void kernel_launch(void* const* d_in, const int* in_sizes, int n_in,
                              void* d_out, int out_size, void* d_ws,
                              size_t ws_size, hipStream_t stream) {
  const float* x       = (const float*)d_in[0];
  const float* listT   = (const float*)d_in[1];
  const float* plb     = (const float*)d_in[2];
  const float* dmod    = (const float*)d_in[3];
  const float* fm_W1   = (const float*)d_in[4];
  const float* fm_b1   = (const float*)d_in[5];
  const float* fm_W2   = (const float*)d_in[6];
  const float* fm_b2   = (const float*)d_in[7];
  const float* fscale  = (const float*)d_in[8];
  const float* U_re    = (const float*)d_in[9];
  const float* U_im    = (const float*)d_in[10];
  const float* V_re    = (const float*)d_in[11];
  const float* V_im    = (const float*)d_in[12];
  const float* pW_re   = (const float*)d_in[13];
  const float* pW_im   = (const float*)d_in[14];
  // d_in[15..16] pb_re/pb_im: cropped out, no effect
  const float* convr_w = (const float*)d_in[17];
  // convr_b/convi_b/projc_b (18,20,22): constant over [S,W] -> cancel in LN
  const float* convi_w = (const float*)d_in[19];
  const float* projc_w = (const float*)d_in[21];
  const float* ln_w    = (const float*)d_in[23];
  const float* ln_b    = (const float*)d_in[24];
  float* out = (float*)d_out;

  float* wsf = (float*)d_ws;
  // R0a [0, 8388608): hs (u32 packed bf16) -> later hsp (alias)
  unsigned* hs  = (unsigned*)wsf;
  unsigned* hsp = (unsigned*)wsf;
  // R0b [8388608, 16777216): coeff mats (dead before conv), then convout+stats
  unsigned* zqAp  = (unsigned*)(wsf + 8388608);           // 262144 u32
  unsigned* recAp = (unsigned*)(wsf + 8388608 + 262144);  // 131072 u32
  unsigned* recBp = (unsigned*)(wsf + 8388608 + 393216);  // 131072 u32
  unsigned short* convout = (unsigned short*)(wsf + 8388608);  // 8388608 u16
  float2*   stats = (float2*)(wsf + 12582912);            // 131072 float2
  float2*   zq  = (float2*)(wsf + 16777216);              // 4,194,304 fl
  size_t off = 16777216 + 4194304;
  // zs: packed bf16 u32; separate region if ws allows, else overlaid on zq.
  const size_t tail = 238592;  // lam+gam+ctxp+Wtb
  unsigned* zs;
  int zst;
  size_t off2;
  if (ws_size >= (off + 2097152 + tail) * 4) {
    zs = (unsigned*)(wsf + off); zst = 1; off2 = off + 2097152;
  } else {
    zs = (unsigned*)zq; zst = 2; off2 = off;
  }
  float2*   lam  = (float2*)(wsf + off2);                 // 131,072 fl
  float*    gam  = wsf + off2 + 131072;                   // 65,536 fl
  float*    ctxp = wsf + off2 + 196608;                   // 32,768 fl
  unsigned* Wtb  = (unsigned*)(wsf + off2 + 229376);      // 9,216 u32

  k_mixprep<<<612, 256, 0, stream>>>(x, pW_re, pW_im, U_re, U_im, V_re, V_im,
                                     projc_w, convr_w, convi_w, hs, ctxp,
                                     zqAp, recAp, recBp, Wtb);
  k_zq<<<576, 256, 0, stream>>>(hs, (const short*)zqAp, zq, ctxp, listT, plb,
                                dmod, fm_W1, fm_b1, fm_W2, fm_b2, fscale,
                                lam, gam);
  k_scan<<<1024, 256, 0, stream>>>(lam, gam, zq, zs, zst);
  k_rec<<<512, 256, 0, stream>>>(zs, zst, (const short*)recAp,
                                 (const short*)recBp, hsp);
  k_conv<<<512, 256, 0, stream>>>(hsp, (const short*)Wtb, convout, stats);
  k_ln<<<1024, 256, 0, stream>>>(convout, stats, x, ln_w, ln_b, out);
}